// Round 4
// baseline (385.089 us; speedup 1.0000x reference)
//
#include <hip/hip_runtime.h>
#include <hip/hip_bf16.h>
#include <math.h>

#define NB 2
#define C1 64
#define C2 256
#define DD 256
#define NHH 8
#define HDD 32
#define NN 4096
#define FF 1024
#define MTOT (NB*NN)   // 8192 tokens
#define KVB 128

typedef unsigned short u16;
typedef __attribute__((ext_vector_type(8))) short bf16x8;
typedef __attribute__((ext_vector_type(4))) short s16x4;
typedef __attribute__((ext_vector_type(4))) float f32x4;
typedef __attribute__((ext_vector_type(4))) unsigned short us4;
typedef __attribute__((ext_vector_type(4))) unsigned int u32x4;

__device__ __forceinline__ u16 f2bf(float f) {
    union { float f; unsigned int i; } u; u.f = f;
    unsigned int r = u.i + 0x7FFFu + ((u.i >> 16) & 1u);
    return (u16)(r >> 16);
}

__device__ __forceinline__ unsigned cvt_pk_bf16(float a, float b) {
    unsigned r; asm("v_cvt_pk_bf16_f32 %0, %1, %2" : "=v"(r) : "v"(a), "v"(b)); return r;
}

// ---------------------------------------------------------------------------
// Weight f32 -> bf16 conversion (all 7 weight matrices, concatenated)
// ---------------------------------------------------------------------------
__global__ __launch_bounds__(256) void wconv(
    const float* __restrict__ s0, const float* __restrict__ s1,
    const float* __restrict__ s2, const float* __restrict__ s3,
    const float* __restrict__ s4, const float* __restrict__ s5,
    const float* __restrict__ s6, u16* __restrict__ d)
{
    int i = blockIdx.x * 256 + threadIdx.x;
    if (i >= 753664) return;
    const float* s; int off;
    if      (i <  16384) { s = s0; off = i; }
    else if (i <  81920) { s = s1; off = i -  16384; }
    else if (i < 147456) { s = s2; off = i -  81920; }
    else if (i < 212992) { s = s3; off = i - 147456; }
    else if (i < 229376) { s = s4; off = i - 212992; }
    else if (i < 491520) { s = s5; off = i - 229376; }
    else                 { s = s6; off = i - 491520; }
    d[i] = f2bf(s[off]);
}

// ---------------------------------------------------------------------------
// (B, C, N) f32  ->  (B, N, C) bf16   (channels-first to token-major)
// ---------------------------------------------------------------------------
__global__ __launch_bounds__(256) void tconv(const float* __restrict__ src,
                                             u16* __restrict__ dst, int C)
{
    __shared__ float tile[64][65];
    const int n0 = blockIdx.x * 64;
    const int c0 = blockIdx.y * 64;
    const int b  = blockIdx.z;
    const int t  = threadIdx.x;
#pragma unroll
    for (int i = 0; i < 4; ++i) {
        int cc = t + i * 256;
        int c = cc >> 4, off = (cc & 15) * 4;
        const float4 v = *(const float4*)&src[((size_t)b*C + c0 + c)*NN + n0 + off];
        tile[c][off+0] = v.x; tile[c][off+1] = v.y;
        tile[c][off+2] = v.z; tile[c][off+3] = v.w;
    }
    __syncthreads();
    const int n = t >> 2, cch = (t & 3) * 16;
    bf16x8 t0, t1;
#pragma unroll
    for (int i = 0; i < 8; ++i) ((u16*)&t0)[i] = f2bf(tile[cch + i][n]);
#pragma unroll
    for (int i = 0; i < 8; ++i) ((u16*)&t1)[i] = f2bf(tile[cch + 8 + i][n]);
    u16* dp = &dst[((size_t)b*NN + n0 + n)*C + c0 + cch];
    *(bf16x8*)&dp[0] = t0;
    *(bf16x8*)&dp[8] = t1;
}

// ---------------------------------------------------------------------------
// Generic C = A * B^T  (A: M x K row-major bf16, B: N x K row-major bf16)
// 128x128 tile, 4 waves (2x2 of 64x64), 16x16x32 bf16 MFMA, BK=32.
// Epilogues:
//  0: QKV-layout bf16 store ((b,h,n,hd)), value*scale
//  1: f32 row-major (resid)
//  2: f32 = acc + add[idx]             (Wo out + resid)
//  3: bf16 relu(acc + bias[col])       (FFN1)
//  4: f32 = acc + bias[col] + add[idx] (FFN2 + skip)
//  5: V^T layout bf16 store: row=(h,hd), col=(b,n) -> [(b*8+h)*32+hd][n]
// ---------------------------------------------------------------------------
template<int MODE>
__global__ __launch_bounds__(256) void gemm_bt(
    const u16* __restrict__ A, const u16* __restrict__ Bw,
    int M, int N, int K,
    const float* __restrict__ bias, const float* __restrict__ add,
    float* __restrict__ outf, u16* __restrict__ outb, float scale)
{
    __shared__ u16 lA[128*40];
    __shared__ u16 lB[128*40];
    const int bm = blockIdx.x * 128;
    const int bn = blockIdx.y * 128;
    const int t = threadIdx.x;
    const int lane = t & 63;
    const int wid = t >> 6;
    const int wr = (wid >> 1) * 64, wc = (wid & 1) * 64;
    const int lrow = lane & 15, lk = (lane >> 4) * 8;
    f32x4 acc[4][4] = {};
    for (int k0 = 0; k0 < K; k0 += 32) {
#pragma unroll
        for (int i = 0; i < 2; ++i) {
            int c = t + i * 256;
            int row = c >> 2, off = (c & 3) * 8;
            *(bf16x8*)&lA[row*40 + off] = *(const bf16x8*)&A[(size_t)(bm+row)*K + k0 + off];
            *(bf16x8*)&lB[row*40 + off] = *(const bf16x8*)&Bw[(size_t)(bn+row)*K + k0 + off];
        }
        __syncthreads();
        bf16x8 af[4], bfr[4];
#pragma unroll
        for (int mf = 0; mf < 4; ++mf)
            af[mf] = *(const bf16x8*)&lA[(wr + mf*16 + lrow)*40 + lk];
#pragma unroll
        for (int nf = 0; nf < 4; ++nf)
            bfr[nf] = *(const bf16x8*)&lB[(wc + nf*16 + lrow)*40 + lk];
#pragma unroll
        for (int mf = 0; mf < 4; ++mf)
#pragma unroll
            for (int nf = 0; nf < 4; ++nf)
                acc[mf][nf] = __builtin_amdgcn_mfma_f32_16x16x32_bf16(af[mf], bfr[nf], acc[mf][nf], 0, 0, 0);
        __syncthreads();
    }
#pragma unroll
    for (int mf = 0; mf < 4; ++mf) {
#pragma unroll
        for (int nf = 0; nf < 4; ++nf) {
#pragma unroll
            for (int j = 0; j < 4; ++j) {
                int row = bm + wr + mf*16 + (lane >> 4)*4 + j;
                int col = bn + wc + nf*16 + lrow;
                float v = acc[mf][nf][j];
                if (MODE == 0) {
                    int b = row >> 12, n = row & 4095;
                    int h = col >> 5, hd = col & 31;
                    outb[(((size_t)b*NHH + h)*NN + n)*HDD + hd] = f2bf(v * scale);
                } else if (MODE == 1) {
                    outf[(size_t)row*N + col] = v;
                } else if (MODE == 2) {
                    size_t idx = (size_t)row*N + col;
                    outf[idx] = v + add[idx];
                } else if (MODE == 3) {
                    float r = v + bias[col];
                    outb[(size_t)row*N + col] = f2bf(r > 0.f ? r : 0.f);
                } else if (MODE == 4) {
                    size_t idx = (size_t)row*N + col;
                    outf[idx] = v + bias[col] + add[idx];
                } else {
                    // V^T: row = d-index (h=row>>5, hd=row&31), col = token
                    int b = col >> 12, n = col & 4095;
                    outb[(((size_t)b*NHH + (row >> 5))*HDD + (row & 31))*NN + n] = f2bf(v);
                }
            }
        }
    }
}

// ---------------------------------------------------------------------------
// Flash attention v3: ZERO LDS, ZERO barriers.
// - no-max base-2 softmax (scores bounded; scale+log2e folded into Q)
// - swapped QK^T: s[nf] = mfma(kf, qf) -> lane holds P-row segment for
//   q = lane&15, keys = nf*16 + g*4 + jj (g = lane>>4) -- lane-local row.
// - PV uses the k-slot permutation slot(g,j) = 32kk + 16*(j>>2) + g*4 + (j&3):
//   the A-frag (P) is exactly the lane's own 8 values (cvt_pk, no cross-lane);
//   the B-frag is V^T (global layout (b,h,hd,n)) read as 2x8B loads from L2.
// - XCD swizzle: each XCD's 128 blocks cover 2 (b,h) pairs -> K/V^T L2-resident.
// ---------------------------------------------------------------------------
__global__ __launch_bounds__(256) void flash_attn(
    const u16* __restrict__ Qp, const u16* __restrict__ Kp,
    const u16* __restrict__ Vtg, u16* __restrict__ Op)
{
    const int id = blockIdx.x;                 // 0..1023
    const int sw = (id & 7) * 128 + (id >> 3); // XCD-grouped
    const int qt = sw & 63;
    const int bh = sw >> 6;                    // b*8 + h
    const size_t base  = (size_t)bh * NN * HDD;   // Q/K (b,h,n,hd)
    const size_t vbase = (size_t)bh * HDD * NN;   // V^T (b,h,hd,n)
    const int t = threadIdx.x, lane = t & 63, w = t >> 6;
    const int q0 = qt * 64;
    const int lrow = lane & 15, g = lane >> 4;

    const bf16x8 qf = *(const bf16x8*)&Qp[base + (size_t)(q0 + w*16 + lrow)*HDD + g*8];
    const u16* krow = &Kp[base + (size_t)lrow*HDD + g*8];           // + key*32
    const u16* vrow0 = &Vtg[vbase + (size_t)lrow*NN + g*4];         // d = lrow
    const u16* vrow1 = vrow0 + (size_t)16*NN;                       // d = 16+lrow

    f32x4 o[2] = {};
    float lrun = 0.f;

    for (int kv0 = 0; kv0 < NN; kv0 += KVB) {
        // S^T = K Q^T : lane -> q = lrow, keys nf*16 + g*4 + jj
        f32x4 s[8];
#pragma unroll
        for (int nf = 0; nf < 8; ++nf) {
            bf16x8 kf = *(const bf16x8*)&krow[(size_t)(kv0 + nf*16)*HDD];
            f32x4 z = {};
            s[nf] = __builtin_amdgcn_mfma_f32_16x16x32_bf16(kf, qf, z, 0, 0, 0);
        }
        // softmax + PV per 32-key block kk (keys 32kk..32kk+31)
#pragma unroll
        for (int kk = 0; kk < 4; ++kk) {
            float p0[4], p1[4];
#pragma unroll
            for (int jj = 0; jj < 4; ++jj) {
                p0[jj] = exp2f(s[2*kk][jj]);
                p1[jj] = exp2f(s[2*kk+1][jj]);
            }
#pragma unroll
            for (int jj = 0; jj < 4; ++jj) lrun += p0[jj] + p1[jj];
            u32x4 paw;
            paw[0] = cvt_pk_bf16(p0[0], p0[1]);
            paw[1] = cvt_pk_bf16(p0[2], p0[3]);
            paw[2] = cvt_pk_bf16(p1[0], p1[1]);
            paw[3] = cvt_pk_bf16(p1[2], p1[3]);
            bf16x8 pa = *(bf16x8*)&paw;
            // B-frag: V^T[d][kv0+32kk+16*(j>>2)+g*4+(j&3)]
#pragma unroll
            for (int hf = 0; hf < 2; ++hf) {
                const u16* vp = (hf ? vrow1 : vrow0) + kv0 + kk*32;
                bf16x8 vf;
                ((s16x4*)&vf)[0] = *(const s16x4*)&vp[0];
                ((s16x4*)&vf)[1] = *(const s16x4*)&vp[16];
                o[hf] = __builtin_amdgcn_mfma_f32_16x16x32_bf16(pa, vf, o[hf], 0, 0, 0);
            }
        }
    }
    // full row sums: reduce across the 4 g-groups (lanes l, l^16, l^32)
    lrun += __shfl_xor(lrun, 16);
    lrun += __shfl_xor(lrun, 32);
    const float inv = 1.f / lrun;              // for q-row = lane&15
    float invr[4];
#pragma unroll
    for (int r = 0; r < 4; ++r)
        invr[r] = __shfl(inv, g*4 + r);        // group-0 lane holding that q
    // O: lane -> d = hf*16 + lrow, q = q0 + w*16 + g*4 + r ; store (b,n,D)
    const int b = bh >> 3, h = bh & 7;
#pragma unroll
    for (int hf = 0; hf < 2; ++hf)
#pragma unroll
        for (int r = 0; r < 4; ++r) {
            int q = q0 + w*16 + g*4 + r;
            int d = h*HDD + hf*16 + lrow;
            Op[((size_t)b*NN + q)*DD + d] = f2bf(o[hf][r] * invr[r]);
        }
}

// ---------------------------------------------------------------------------
// LayerNorm1: y (8192x256 f32) -> x f32 and x bf16. One wave per row.
// ---------------------------------------------------------------------------
__global__ __launch_bounds__(256) void ln_fuse(const float* __restrict__ y,
    const float* __restrict__ g, const float* __restrict__ be,
    float* __restrict__ x, u16* __restrict__ xb)
{
    const int row = blockIdx.x * 4 + (threadIdx.x >> 6);
    const int lane = threadIdx.x & 63;
    const float4 v = *(const float4*)&y[(size_t)row*DD + lane*4];
    float s1 = v.x + v.y + v.z + v.w;
    float s2 = v.x*v.x + v.y*v.y + v.z*v.z + v.w*v.w;
#pragma unroll
    for (int m = 1; m <= 32; m <<= 1) { s1 += __shfl_xor(s1, m); s2 += __shfl_xor(s2, m); }
    float mean = s1 * (1.f/DD);
    float var  = s2 * (1.f/DD) - mean*mean;
    float rstd = rsqrtf(var + 1e-5f);
    const float vv[4] = {v.x, v.y, v.z, v.w};
    float4 xo; us4 xo16;
#pragma unroll
    for (int i = 0; i < 4; ++i) {
        int d = lane*4 + i;
        float r = (vv[i] - mean) * rstd * g[d] + be[d];
        ((float*)&xo)[i] = r;
        xo16[i] = f2bf(r);
    }
    *(float4*)&x[(size_t)row*DD + lane*4] = xo;
    *(us4*)&xb[(size_t)row*DD + lane*4] = xo16;
}

// ---------------------------------------------------------------------------
// LayerNorm2 + transpose to (B, D, H*W). 32 tokens per block via LDS tile.
// ---------------------------------------------------------------------------
__global__ __launch_bounds__(256) void ln2_transpose(const float* __restrict__ z,
    const float* __restrict__ g, const float* __restrict__ be,
    float* __restrict__ out)
{
    __shared__ float tile[32][257];
    const int n0 = blockIdx.x * 32;
    const int b = blockIdx.y;
    const int t = threadIdx.x, lane = t & 63, w = t >> 6;
    for (int r8 = 0; r8 < 8; ++r8) {
        int r = w*8 + r8;
        const float4 v = *(const float4*)&z[((size_t)b*NN + n0 + r)*DD + lane*4];
        float s1 = v.x + v.y + v.z + v.w;
        float s2 = v.x*v.x + v.y*v.y + v.z*v.z + v.w*v.w;
#pragma unroll
        for (int m = 1; m <= 32; m <<= 1) { s1 += __shfl_xor(s1, m); s2 += __shfl_xor(s2, m); }
        float mean = s1 * (1.f/DD);
        float var  = s2 * (1.f/DD) - mean*mean;
        float rstd = rsqrtf(var + 1e-5f);
        const float vv[4] = {v.x, v.y, v.z, v.w};
#pragma unroll
        for (int i = 0; i < 4; ++i) {
            int d = lane*4 + i;
            tile[r][d] = (vv[i] - mean)*rstd*g[d] + be[d];
        }
    }
    __syncthreads();
    const int n = t & 31, dg = t >> 5;
    for (int dd = 0; dd < 32; ++dd) {
        int d = dd*8 + dg;
        out[((size_t)b*DD + d)*NN + n0 + n] = tile[n][d];
    }
}

// ---------------------------------------------------------------------------
extern "C" void kernel_launch(void* const* d_in, const int* in_sizes, int n_in,
                              void* d_out, int out_size, void* d_ws, size_t ws_size,
                              hipStream_t stream)
{
    const float* F_lidar = (const float*)d_in[0];
    const float* F_cam   = (const float*)d_in[1];
    const float* Wq  = (const float*)d_in[2];
    const float* Wk  = (const float*)d_in[3];
    const float* Wv  = (const float*)d_in[4];
    const float* Wo  = (const float*)d_in[5];
    const float* Wrs = (const float*)d_in[6];
    const float* g1  = (const float*)d_in[7];
    const float* b1  = (const float*)d_in[8];
    const float* g2  = (const float*)d_in[9];
    const float* b2  = (const float*)d_in[10];
    const float* W1  = (const float*)d_in[11];
    const float* bf1 = (const float*)d_in[12];
    const float* W2  = (const float*)d_in[13];
    const float* bf2 = (const float*)d_in[14];
    float* out = (float*)d_out;

    char* ws = (char*)d_ws;
    size_t cur = 0;
    auto carve = [&](size_t bytes) {
        size_t o = cur; cur += (bytes + 255) & ~(size_t)255; return (void*)(ws + o);
    };
    u16* wb    = (u16*)carve(753664u * 2);
    u16* xl    = (u16*)carve((size_t)MTOT * C1 * 2);
    u16* xc    = (u16*)carve((size_t)MTOT * C2 * 2);
    u16* Qb    = (u16*)carve((size_t)MTOT * DD * 2);
    u16* Kb    = (u16*)carve((size_t)MTOT * DD * 2);
    u16* Vtg   = (u16*)carve((size_t)MTOT * DD * 2);
    float* resid = (float*)carve((size_t)MTOT * DD * 4);
    u16* attn  = (u16*)carve((size_t)MTOT * DD * 2);
    float* y   = (float*)carve((size_t)MTOT * DD * 4);
    float* x   = (float*)carve((size_t)MTOT * DD * 4);
    u16* xb    = (u16*)carve((size_t)MTOT * DD * 2);
    u16* hdn   = (u16*)carve((size_t)MTOT * FF * 2);
    float* zb  = y;   // reuse: y consumed by ln_fuse before FFN2 writes z

    u16* Wqb  = wb;
    u16* Wkb  = wb + 16384;
    u16* Wvb  = wb + 81920;
    u16* Wob  = wb + 147456;
    u16* Wrsb = wb + 212992;
    u16* W1b  = wb + 229376;
    u16* W2b  = wb + 491520;

    wconv<<<2944, 256, 0, stream>>>(Wq, Wk, Wv, Wo, Wrs, W1, W2, wb);
    tconv<<<dim3(64, 1, NB), 256, 0, stream>>>(F_lidar, xl, C1);
    tconv<<<dim3(64, 4, NB), 256, 0, stream>>>(F_cam, xc, C2);

    // softmax scale and log2(e) folded into Q
    const float qscale = 1.4426950408889634f / sqrtf((float)HDD);
    gemm_bt<0><<<dim3(64, 2), 256, 0, stream>>>(xl, Wqb, MTOT, DD, C1, nullptr, nullptr, nullptr, Qb, qscale);
    gemm_bt<0><<<dim3(64, 2), 256, 0, stream>>>(xc, Wkb, MTOT, DD, C2, nullptr, nullptr, nullptr, Kb, 1.f);
    // V^T = Wv * xc^T  (A = Wv 256x256, B = xc 8192x256) -> (b,h,hd,n)
    gemm_bt<5><<<dim3(2, 64), 256, 0, stream>>>(Wvb, xc, DD, MTOT, C2, nullptr, nullptr, nullptr, Vtg, 1.f);
    gemm_bt<1><<<dim3(64, 2), 256, 0, stream>>>(xl, Wrsb, MTOT, DD, C1, nullptr, nullptr, resid, nullptr, 1.f);

    flash_attn<<<1024, 256, 0, stream>>>(Qb, Kb, Vtg, attn);

    gemm_bt<2><<<dim3(64, 2), 256, 0, stream>>>(attn, Wob, MTOT, DD, DD, nullptr, resid, y, nullptr, 1.f);
    ln_fuse<<<2048, 256, 0, stream>>>(y, g1, b1, x, xb);
    gemm_bt<3><<<dim3(64, 8), 256, 0, stream>>>(xb, W1b, MTOT, FF, DD, bf1, nullptr, nullptr, hdn, 1.f);
    gemm_bt<4><<<dim3(64, 2), 256, 0, stream>>>(hdn, W2b, MTOT, DD, FF, bf2, x, zb, nullptr, 1.f);
    ln2_transpose<<<dim3(128, NB), 256, 0, stream>>>(zb, g2, b2, out);
}

// Round 5
// 195.103 us; speedup vs baseline: 1.9738x; 1.9738x over previous
//
#include <hip/hip_runtime.h>
#include <hip/hip_bf16.h>
#include <math.h>

#define NB 2
#define C1 64
#define C2 256
#define DD 256
#define NHH 8
#define HDD 32
#define NN 4096
#define FF 1024
#define MTOT (NB*NN)   // 8192 tokens
#define KVB 128

typedef unsigned short u16;
typedef __attribute__((ext_vector_type(8))) short bf16x8;
typedef __attribute__((ext_vector_type(4))) short s16x4;
typedef __attribute__((ext_vector_type(4))) float f32x4;
typedef __attribute__((ext_vector_type(4))) unsigned short us4;
typedef __attribute__((ext_vector_type(4))) unsigned int u32x4;

__device__ __forceinline__ u16 f2bf(float f) {
    union { float f; unsigned int i; } u; u.f = f;
    unsigned int r = u.i + 0x7FFFu + ((u.i >> 16) & 1u);
    return (u16)(r >> 16);
}

__device__ __forceinline__ unsigned cvt_pk_bf16(float a, float b) {
    unsigned r; asm("v_cvt_pk_bf16_f32 %0, %1, %2" : "=v"(r) : "v"(a), "v"(b)); return r;
}

// ---------------------------------------------------------------------------
// Weight f32 -> bf16 conversion (all 7 weight matrices, concatenated)
// ---------------------------------------------------------------------------
__global__ __launch_bounds__(256) void wconv(
    const float* __restrict__ s0, const float* __restrict__ s1,
    const float* __restrict__ s2, const float* __restrict__ s3,
    const float* __restrict__ s4, const float* __restrict__ s5,
    const float* __restrict__ s6, u16* __restrict__ d)
{
    int i = blockIdx.x * 256 + threadIdx.x;
    if (i >= 753664) return;
    const float* s; int off;
    if      (i <  16384) { s = s0; off = i; }
    else if (i <  81920) { s = s1; off = i -  16384; }
    else if (i < 147456) { s = s2; off = i -  81920; }
    else if (i < 212992) { s = s3; off = i - 147456; }
    else if (i < 229376) { s = s4; off = i - 212992; }
    else if (i < 491520) { s = s5; off = i - 229376; }
    else                 { s = s6; off = i - 491520; }
    d[i] = f2bf(s[off]);
}

// ---------------------------------------------------------------------------
// (B, C, N) f32  ->  (B, N, C) bf16   (channels-first to token-major)
// ---------------------------------------------------------------------------
__global__ __launch_bounds__(256) void tconv(const float* __restrict__ src,
                                             u16* __restrict__ dst, int C)
{
    __shared__ float tile[64][65];
    const int n0 = blockIdx.x * 64;
    const int c0 = blockIdx.y * 64;
    const int b  = blockIdx.z;
    const int t  = threadIdx.x;
#pragma unroll
    for (int i = 0; i < 4; ++i) {
        int cc = t + i * 256;
        int c = cc >> 4, off = (cc & 15) * 4;
        const float4 v = *(const float4*)&src[((size_t)b*C + c0 + c)*NN + n0 + off];
        tile[c][off+0] = v.x; tile[c][off+1] = v.y;
        tile[c][off+2] = v.z; tile[c][off+3] = v.w;
    }
    __syncthreads();
    const int n = t >> 2, cch = (t & 3) * 16;
    bf16x8 t0, t1;
#pragma unroll
    for (int i = 0; i < 8; ++i) ((u16*)&t0)[i] = f2bf(tile[cch + i][n]);
#pragma unroll
    for (int i = 0; i < 8; ++i) ((u16*)&t1)[i] = f2bf(tile[cch + 8 + i][n]);
    u16* dp = &dst[((size_t)b*NN + n0 + n)*C + c0 + cch];
    *(bf16x8*)&dp[0] = t0;
    *(bf16x8*)&dp[8] = t1;
}

// ---------------------------------------------------------------------------
// Generic C = A * B^T  (A: M x K row-major bf16, B: N x K row-major bf16)
// 128x128 tile, 4 waves (2x2 of 64x64), 16x16x32 bf16 MFMA, BK=32.
// Epilogues:
//  0: QKV-layout bf16 store ((b,h,n,hd)), value*scale
//  1: f32 row-major (resid)
//  2: f32 = acc + add[idx]             (Wo out + resid)
//  3: bf16 relu(acc + bias[col])       (FFN1)
//  4: f32 = acc + bias[col] + add[idx] (FFN2 + skip)
//  5: V fragment-permuted layout for flash PV B-frags (see flash_attn)
// ---------------------------------------------------------------------------
template<int MODE>
__global__ __launch_bounds__(256) void gemm_bt(
    const u16* __restrict__ A, const u16* __restrict__ Bw,
    int M, int N, int K,
    const float* __restrict__ bias, const float* __restrict__ add,
    float* __restrict__ outf, u16* __restrict__ outb, float scale)
{
    __shared__ u16 lA[128*40];
    __shared__ u16 lB[128*40];
    const int bm = blockIdx.x * 128;
    const int bn = blockIdx.y * 128;
    const int t = threadIdx.x;
    const int lane = t & 63;
    const int wid = t >> 6;
    const int wr = (wid >> 1) * 64, wc = (wid & 1) * 64;
    const int lrow = lane & 15, lk = (lane >> 4) * 8;
    f32x4 acc[4][4] = {};
    for (int k0 = 0; k0 < K; k0 += 32) {
#pragma unroll
        for (int i = 0; i < 2; ++i) {
            int c = t + i * 256;
            int row = c >> 2, off = (c & 3) * 8;
            *(bf16x8*)&lA[row*40 + off] = *(const bf16x8*)&A[(size_t)(bm+row)*K + k0 + off];
            *(bf16x8*)&lB[row*40 + off] = *(const bf16x8*)&Bw[(size_t)(bn+row)*K + k0 + off];
        }
        __syncthreads();
        bf16x8 af[4], bfr[4];
#pragma unroll
        for (int mf = 0; mf < 4; ++mf)
            af[mf] = *(const bf16x8*)&lA[(wr + mf*16 + lrow)*40 + lk];
#pragma unroll
        for (int nf = 0; nf < 4; ++nf)
            bfr[nf] = *(const bf16x8*)&lB[(wc + nf*16 + lrow)*40 + lk];
#pragma unroll
        for (int mf = 0; mf < 4; ++mf)
#pragma unroll
            for (int nf = 0; nf < 4; ++nf)
                acc[mf][nf] = __builtin_amdgcn_mfma_f32_16x16x32_bf16(af[mf], bfr[nf], acc[mf][nf], 0, 0, 0);
        __syncthreads();
    }
#pragma unroll
    for (int mf = 0; mf < 4; ++mf) {
#pragma unroll
        for (int nf = 0; nf < 4; ++nf) {
#pragma unroll
            for (int j = 0; j < 4; ++j) {
                int row = bm + wr + mf*16 + (lane >> 4)*4 + j;
                int col = bn + wc + nf*16 + lrow;
                float v = acc[mf][nf][j];
                if (MODE == 0) {
                    int b = row >> 12, n = row & 4095;
                    int h = col >> 5, hd = col & 31;
                    outb[(((size_t)b*NHH + h)*NN + n)*HDD + hd] = f2bf(v * scale);
                } else if (MODE == 1) {
                    outf[(size_t)row*N + col] = v;
                } else if (MODE == 2) {
                    size_t idx = (size_t)row*N + col;
                    outf[idx] = v + add[idx];
                } else if (MODE == 3) {
                    float r = v + bias[col];
                    outb[(size_t)row*N + col] = f2bf(r > 0.f ? r : 0.f);
                } else if (MODE == 4) {
                    size_t idx = (size_t)row*N + col;
                    outf[idx] = v + bias[col] + add[idx];
                } else {
                    // MODE 5: V fragment-permuted scatter.
                    // value = V[token=col][d_full=row]
                    // dest element: [bh][kb=n>>5][hf][g][d][ hp*4 + r ]
                    int b = col >> 12, n = col & 4095;
                    int h = row >> 5, hd = row & 31;
                    int hf = hd >> 4, d = hd & 15;
                    int bh = b*NHH + h;
                    int kb = n >> 5, kwb = n & 31;
                    int hp = kwb >> 4, gg = (kwb >> 2) & 3, r = kwb & 3;
                    size_t idx = ((((size_t)bh*128 + kb)*2 + hf)*64 + gg*16 + d)*8
                               + hp*4 + r;
                    outb[idx] = f2bf(v);
                }
            }
        }
    }
}

// ---------------------------------------------------------------------------
// Flash attention v5: ZERO LDS, ZERO barriers, fully-coalesced loads.
// - no-max base-2 softmax (scores bounded; scale+log2e folded into Q)
// - swapped QK^T: s[nf] = mfma(kf, qf) -> lane holds S for q = lane&15,
//   keys = nf*16 + g*4 + jj (g = lane>>4): lane-local row segment.
// - PV k-slot permutation slot(g,j) = 32kk + 16*(j>>2) + g*4 + (j&3):
//   A-frag = lane's own 8 P values (cvt_pk, no cross-lane);
//   B-frag = ONE 16B load from the fragment-permuted V buffer (MODE 5):
//   wave reads 1KB contiguous per (kk,hf) -- same shape as K loads.
// - XCD swizzle: each XCD's 128 blocks cover 2 (b,h) pairs -> K/V L2-resident.
// ---------------------------------------------------------------------------
__global__ __launch_bounds__(256) void flash_attn(
    const u16* __restrict__ Qp, const u16* __restrict__ Kp,
    const u16* __restrict__ Vperm, u16* __restrict__ Op)
{
    const int id = blockIdx.x;                 // 0..1023
    const int sw = (id & 7) * 128 + (id >> 3); // XCD-grouped
    const int qt = sw & 63;
    const int bh = sw >> 6;                    // b*8 + h
    const size_t base = (size_t)bh * NN * HDD; // Q/K (b,h,n,hd)
    const int t = threadIdx.x, lane = t & 63, w = t >> 6;
    const int q0 = qt * 64;
    const int lrow = lane & 15, g = lane >> 4;

    const bf16x8 qf = *(const bf16x8*)&Qp[base + (size_t)(q0 + w*16 + lrow)*HDD + g*8];
    const u16* krow  = &Kp[base + (size_t)lrow*HDD + g*8];           // + key*HDD
    const u16* vlane = &Vperm[(size_t)bh*131072 + g*128 + lrow*8];   // + kb*1024 + hf*512

    f32x4 o[2] = {};
    float lrun = 0.f;

    for (int kv0 = 0; kv0 < NN; kv0 += KVB) {
        // S^T = K Q^T : lane -> q = lrow, keys nf*16 + g*4 + jj
        f32x4 s[8];
#pragma unroll
        for (int nf = 0; nf < 8; ++nf) {
            bf16x8 kf = *(const bf16x8*)&krow[(size_t)(kv0 + nf*16)*HDD];
            f32x4 z = {};
            s[nf] = __builtin_amdgcn_mfma_f32_16x16x32_bf16(kf, qf, z, 0, 0, 0);
        }
        // softmax + PV per 32-key block kk
#pragma unroll
        for (int kk = 0; kk < 4; ++kk) {
            const int kb = (kv0 >> 5) + kk;
            float p0[4], p1[4];
#pragma unroll
            for (int jj = 0; jj < 4; ++jj) {
                p0[jj] = exp2f(s[2*kk][jj]);
                p1[jj] = exp2f(s[2*kk+1][jj]);
            }
#pragma unroll
            for (int jj = 0; jj < 4; ++jj) lrun += p0[jj] + p1[jj];
            u32x4 paw;
            paw[0] = cvt_pk_bf16(p0[0], p0[1]);
            paw[1] = cvt_pk_bf16(p0[2], p0[3]);
            paw[2] = cvt_pk_bf16(p1[0], p1[1]);
            paw[3] = cvt_pk_bf16(p1[2], p1[3]);
            bf16x8 pa = *(bf16x8*)&paw;
#pragma unroll
            for (int hf = 0; hf < 2; ++hf) {
                bf16x8 vf = *(const bf16x8*)&vlane[(size_t)kb*1024 + hf*512];
                o[hf] = __builtin_amdgcn_mfma_f32_16x16x32_bf16(pa, vf, o[hf], 0, 0, 0);
            }
        }
    }
    // full row sums: reduce across the 4 g-groups (lanes l, l^16, l^32)
    lrun += __shfl_xor(lrun, 16);
    lrun += __shfl_xor(lrun, 32);
    const float inv = 1.f / lrun;              // for q-row = lane&15
    float invr[4];
#pragma unroll
    for (int r = 0; r < 4; ++r)
        invr[r] = __shfl(inv, g*4 + r);        // group-0 lane holding that q
    // O: lane -> d = hf*16 + lrow, q = q0 + w*16 + g*4 + r ; store (b,n,D)
    const int b = bh >> 3, h = bh & 7;
#pragma unroll
    for (int hf = 0; hf < 2; ++hf)
#pragma unroll
        for (int r = 0; r < 4; ++r) {
            int q = q0 + w*16 + g*4 + r;
            int d = h*HDD + hf*16 + lrow;
            Op[((size_t)b*NN + q)*DD + d] = f2bf(o[hf][r] * invr[r]);
        }
}

// ---------------------------------------------------------------------------
// LayerNorm1: y (8192x256 f32) -> x f32 and x bf16. One wave per row.
// ---------------------------------------------------------------------------
__global__ __launch_bounds__(256) void ln_fuse(const float* __restrict__ y,
    const float* __restrict__ g, const float* __restrict__ be,
    float* __restrict__ x, u16* __restrict__ xb)
{
    const int row = blockIdx.x * 4 + (threadIdx.x >> 6);
    const int lane = threadIdx.x & 63;
    const float4 v = *(const float4*)&y[(size_t)row*DD + lane*4];
    float s1 = v.x + v.y + v.z + v.w;
    float s2 = v.x*v.x + v.y*v.y + v.z*v.z + v.w*v.w;
#pragma unroll
    for (int m = 1; m <= 32; m <<= 1) { s1 += __shfl_xor(s1, m); s2 += __shfl_xor(s2, m); }
    float mean = s1 * (1.f/DD);
    float var  = s2 * (1.f/DD) - mean*mean;
    float rstd = rsqrtf(var + 1e-5f);
    const float vv[4] = {v.x, v.y, v.z, v.w};
    float4 xo; us4 xo16;
#pragma unroll
    for (int i = 0; i < 4; ++i) {
        int d = lane*4 + i;
        float r = (vv[i] - mean) * rstd * g[d] + be[d];
        ((float*)&xo)[i] = r;
        xo16[i] = f2bf(r);
    }
    *(float4*)&x[(size_t)row*DD + lane*4] = xo;
    *(us4*)&xb[(size_t)row*DD + lane*4] = xo16;
}

// ---------------------------------------------------------------------------
// LayerNorm2 + transpose to (B, D, H*W). 32 tokens per block via LDS tile.
// ---------------------------------------------------------------------------
__global__ __launch_bounds__(256) void ln2_transpose(const float* __restrict__ z,
    const float* __restrict__ g, const float* __restrict__ be,
    float* __restrict__ out)
{
    __shared__ float tile[32][257];
    const int n0 = blockIdx.x * 32;
    const int b = blockIdx.y;
    const int t = threadIdx.x, lane = t & 63, w = t >> 6;
    for (int r8 = 0; r8 < 8; ++r8) {
        int r = w*8 + r8;
        const float4 v = *(const float4*)&z[((size_t)b*NN + n0 + r)*DD + lane*4];
        float s1 = v.x + v.y + v.z + v.w;
        float s2 = v.x*v.x + v.y*v.y + v.z*v.z + v.w*v.w;
#pragma unroll
        for (int m = 1; m <= 32; m <<= 1) { s1 += __shfl_xor(s1, m); s2 += __shfl_xor(s2, m); }
        float mean = s1 * (1.f/DD);
        float var  = s2 * (1.f/DD) - mean*mean;
        float rstd = rsqrtf(var + 1e-5f);
        const float vv[4] = {v.x, v.y, v.z, v.w};
#pragma unroll
        for (int i = 0; i < 4; ++i) {
            int d = lane*4 + i;
            tile[r][d] = (vv[i] - mean)*rstd*g[d] + be[d];
        }
    }
    __syncthreads();
    const int n = t & 31, dg = t >> 5;
    for (int dd = 0; dd < 32; ++dd) {
        int d = dd*8 + dg;
        out[((size_t)b*DD + d)*NN + n0 + n] = tile[n][d];
    }
}

// ---------------------------------------------------------------------------
extern "C" void kernel_launch(void* const* d_in, const int* in_sizes, int n_in,
                              void* d_out, int out_size, void* d_ws, size_t ws_size,
                              hipStream_t stream)
{
    const float* F_lidar = (const float*)d_in[0];
    const float* F_cam   = (const float*)d_in[1];
    const float* Wq  = (const float*)d_in[2];
    const float* Wk  = (const float*)d_in[3];
    const float* Wv  = (const float*)d_in[4];
    const float* Wo  = (const float*)d_in[5];
    const float* Wrs = (const float*)d_in[6];
    const float* g1  = (const float*)d_in[7];
    const float* b1  = (const float*)d_in[8];
    const float* g2  = (const float*)d_in[9];
    const float* b2  = (const float*)d_in[10];
    const float* W1  = (const float*)d_in[11];
    const float* bf1 = (const float*)d_in[12];
    const float* W2  = (const float*)d_in[13];
    const float* bf2 = (const float*)d_in[14];
    float* out = (float*)d_out;

    char* ws = (char*)d_ws;
    size_t cur = 0;
    auto carve = [&](size_t bytes) {
        size_t o = cur; cur += (bytes + 255) & ~(size_t)255; return (void*)(ws + o);
    };
    u16* wb    = (u16*)carve(753664u * 2);
    u16* xl    = (u16*)carve((size_t)MTOT * C1 * 2);
    u16* xc    = (u16*)carve((size_t)MTOT * C2 * 2);
    u16* Qb    = (u16*)carve((size_t)MTOT * DD * 2);
    u16* Kb    = (u16*)carve((size_t)MTOT * DD * 2);
    u16* Vperm = (u16*)carve((size_t)MTOT * DD * 2);
    float* resid = (float*)carve((size_t)MTOT * DD * 4);
    u16* attn  = (u16*)carve((size_t)MTOT * DD * 2);
    float* y   = (float*)carve((size_t)MTOT * DD * 4);
    float* x   = (float*)carve((size_t)MTOT * DD * 4);
    u16* xb    = (u16*)carve((size_t)MTOT * DD * 2);
    u16* hdn   = (u16*)carve((size_t)MTOT * FF * 2);
    float* zb  = y;   // reuse: y consumed by ln_fuse before FFN2 writes z

    u16* Wqb  = wb;
    u16* Wkb  = wb + 16384;
    u16* Wvb  = wb + 81920;
    u16* Wob  = wb + 147456;
    u16* Wrsb = wb + 212992;
    u16* W1b  = wb + 229376;
    u16* W2b  = wb + 491520;

    wconv<<<2944, 256, 0, stream>>>(Wq, Wk, Wv, Wo, Wrs, W1, W2, wb);
    tconv<<<dim3(64, 1, NB), 256, 0, stream>>>(F_lidar, xl, C1);
    tconv<<<dim3(64, 4, NB), 256, 0, stream>>>(F_cam, xc, C2);

    // softmax scale and log2(e) folded into Q
    const float qscale = 1.4426950408889634f / sqrtf((float)HDD);
    gemm_bt<0><<<dim3(64, 2), 256, 0, stream>>>(xl, Wqb, MTOT, DD, C1, nullptr, nullptr, nullptr, Qb, qscale);
    gemm_bt<0><<<dim3(64, 2), 256, 0, stream>>>(xc, Wkb, MTOT, DD, C2, nullptr, nullptr, nullptr, Kb, 1.f);
    // V^T = Wv * xc^T  (A = Wv 256x256, B = xc 8192x256) -> fragment-permuted
    gemm_bt<5><<<dim3(2, 64), 256, 0, stream>>>(Wvb, xc, DD, MTOT, C2, nullptr, nullptr, nullptr, Vperm, 1.f);
    gemm_bt<1><<<dim3(64, 2), 256, 0, stream>>>(xl, Wrsb, MTOT, DD, C1, nullptr, nullptr, resid, nullptr, 1.f);

    flash_attn<<<1024, 256, 0, stream>>>(Qb, Kb, Vperm, attn);

    gemm_bt<2><<<dim3(64, 2), 256, 0, stream>>>(attn, Wob, MTOT, DD, DD, nullptr, resid, y, nullptr, 1.f);
    ln_fuse<<<2048, 256, 0, stream>>>(y, g1, b1, x, xb);
    gemm_bt<3><<<dim3(64, 8), 256, 0, stream>>>(xb, W1b, MTOT, FF, DD, bf1, nullptr, nullptr, hdn, 1.f);
    gemm_bt<4><<<dim3(64, 2), 256, 0, stream>>>(hdn, W2b, MTOT, DD, FF, bf2, x, zb, nullptr, 1.f);
    ln2_transpose<<<dim3(128, NB), 256, 0, stream>>>(zb, g2, b2, out);
}